// Round 6
// baseline (704.428 us; speedup 1.0000x reference)
//
#include <hip/hip_runtime.h>

#define NN 100000   // nodes
#define NE 1600000  // edges
#define NR 8        // relations
#define DD 128      // feature dim
#define NKEY (NN * NR)               // 800000 (dst,rel) keys
#define NBLK ((NKEY + 1023) / 1024)  // 782 scan blocks
#define RSTRIDE 580                  // sAgg row stride in dwords (R3/R5-proven)
#define CSRN 4000256                 // padded csr capacity: NE + 3*NKEY + 256 slack

typedef __attribute__((ext_vector_type(8))) short short8;
typedef __attribute__((ext_vector_type(4))) float f32x4;

__device__ __forceinline__ float bf2f(unsigned short u) {
  union { unsigned int i; float f; } c; c.i = ((unsigned int)u) << 16; return c.f;
}
__device__ __forceinline__ unsigned short f2bf(float f) {
  union { float f; unsigned int i; } c; c.f = f;
  unsigned int u = c.i;
  return (unsigned short)((u + 0x7FFFu + ((u >> 16) & 1u)) >> 16);  // RNE
}

// ---- fused preprocessing: x-cast + zero-row + counter-zero + wtrans + csr-fill
__global__ __launch_bounds__(256) void k_prep(
    const float* __restrict__ x, unsigned short* __restrict__ xb,
    unsigned short* __restrict__ xb2,
    const float* __restrict__ W1, const float* __restrict__ root1,
    const float* __restrict__ W2, const float* __restrict__ root2,
    unsigned short* __restrict__ wbf, int* __restrict__ cnt,
    int* __restrict__ csr) {
  const int CAST_B = (NN * DD / 4 + 255) / 256;   // 12500
  const int ZROW_B = 1;                            // zero rows xb[NN], xb2[NN]
  const int ZCNT_B = (NKEY + 255) / 256;           // 3125
  const int WT_B   = (2 * 9 * 16384) / 256;        // 1152
  int b = blockIdx.x, t = threadIdx.x;
  if (b < CAST_B) {
    int i = b * 256 + t;
    if (i < NN * DD / 4) {
      float4 f = ((const float4*)x)[i];
      ushort4 u;
      u.x = f2bf(f.x); u.y = f2bf(f.y); u.z = f2bf(f.z); u.w = f2bf(f.w);
      ((ushort4*)xb)[i] = u;
    }
  } else if (b < CAST_B + ZROW_B) {
    // dedicated all-zero gather row at node index NN (padding target)
    if (t < 64)       ((unsigned int*)(xb  + (size_t)NN * DD))[t]      = 0;
    else if (t < 128) ((unsigned int*)(xb2 + (size_t)NN * DD))[t - 64] = 0;
  } else if (b < CAST_B + ZROW_B + ZCNT_B) {
    int i = (b - CAST_B - ZROW_B) * 256 + t;
    if (i < NKEY) cnt[i] = 0;
  } else if (b < CAST_B + ZROW_B + ZCNT_B + WT_B) {
    int idx = (b - CAST_B - ZROW_B - ZCNT_B) * 256 + t;  // 2*9*16384 exact
    int layer = idx / (9 * 16384);
    int rem = idx % (9 * 16384);
    int r = rem / 16384;
    int nk = rem % 16384;
    int n = nk >> 7, k = nk & 127;
    float v;
    if (r < 8) v = (layer ? W2 : W1)[r * 16384 + k * 128 + n];
    else       v = (layer ? root2 : root1)[k * 128 + n];
    wbf[idx] = f2bf(v);
  } else {
    // prefill csr with the zero-row index: padding slots gather exact zeros
    int i = (b - CAST_B - ZROW_B - ZCNT_B - WT_B) * 256 + t;
    if (i < CSRN) csr[i] = NN;
  }
}

// count + per-edge rank (returning atomicAdd); cnt holds TRUE counts after.
__global__ __launch_bounds__(256) void k_count(
    const int* __restrict__ ei, const int* __restrict__ et,
    int* __restrict__ cnt, int* __restrict__ rank) {
  int e = blockIdx.x * 256 + threadIdx.x;
  if (e < NE) {
    int dst = ei[NE + e];
    int r = et[e];
    rank[e] = atomicAdd(&cnt[dst * NR + r], 1);
  }
}

// hierarchical exclusive scan over PADDED counts 4*ceil(c/4) — shfl-based
__global__ __launch_bounds__(1024) void k_scan1(
    const int* __restrict__ cnt, int* __restrict__ offs, int* __restrict__ bsum) {
  __shared__ int sw[16];
  int t = threadIdx.x, b = blockIdx.x;
  int lane = t & 63, wid = t >> 6;
  int i = b * 1024 + t;
  int v = (i < NKEY) ? ((cnt[i] + 3) & ~3) : 0;
  int x = v;
#pragma unroll
  for (int o = 1; o < 64; o <<= 1) {
    int y = __shfl_up(x, o);
    if (lane >= o) x += y;
  }
  if (lane == 63) sw[wid] = x;
  __syncthreads();
  if (wid == 0) {
    int s = (lane < 16) ? sw[lane] : 0;
#pragma unroll
    for (int o = 1; o < 16; o <<= 1) {
      int y = __shfl_up(s, o);
      if (lane >= o) s += y;
    }
    if (lane < 16) sw[lane] = s;
  }
  __syncthreads();
  int base = (wid > 0) ? sw[wid - 1] : 0;
  if (i < NKEY) offs[i] = base + x - v;
  if (t == 1023) bsum[b] = base + x;
}

__global__ __launch_bounds__(1024) void k_scan2(int* __restrict__ bsum) {
  __shared__ int sw[16];
  int t = threadIdx.x;
  int lane = t & 63, wid = t >> 6;
  int v = (t < NBLK) ? bsum[t] : 0;
  int x = v;
#pragma unroll
  for (int o = 1; o < 64; o <<= 1) {
    int y = __shfl_up(x, o);
    if (lane >= o) x += y;
  }
  if (lane == 63) sw[wid] = x;
  __syncthreads();
  if (wid == 0) {
    int s = (lane < 16) ? sw[lane] : 0;
#pragma unroll
    for (int o = 1; o < 16; o <<= 1) {
      int y = __shfl_up(s, o);
      if (lane >= o) s += y;
    }
    if (lane < 16) sw[lane] = s;
  }
  __syncthreads();
  int base = (wid > 0) ? sw[wid - 1] : 0;
  if (t < NBLK) bsum[t] = base + x - v;
}

__global__ __launch_bounds__(256) void k_scan3(
    int* __restrict__ offs, const int* __restrict__ bsum, const int* __restrict__ cnt) {
  int i = blockIdx.x * 256 + threadIdx.x;
  if (i < NKEY) {
    offs[i] += bsum[i >> 10];
    if (i == NKEY - 1) offs[NKEY] = offs[i] + ((cnt[i] + 3) & ~3);
  }
}

// pure scatter, no atomics: slot = offs[key] + rank[e] (unique; rank < c <= pc)
__global__ __launch_bounds__(256) void k_csr(
    const int* __restrict__ ei, const int* __restrict__ et,
    const int* __restrict__ offs, const int* __restrict__ rank,
    int* __restrict__ csr) {
  int e = blockIdx.x * 256 + threadIdx.x;
  if (e < NE) {
    int src = ei[e];
    int key = ei[NE + e] * NR + et[e];
    csr[offs[key] + rank[e]] = src;
  }
}

// ---- fused per-layer kernel -------------------------------------------------
// Block (512 thr, 8 waves) owns 32 dst nodes (74.2 KB LDS, 2 blocks/CU).
// R6 edge phase: FOUR edges per gather instruction. Lane l loads 16B of edge
// pos+(l>>4), dims (l&15)*8..+8 — one dwordx4 wave-instruction covers four
// 256B rows. csr segments are padded per key to a multiple of 4 (pad slots
// point at the all-zero row NN), so every aligned 4-group lies inside ONE key:
// no masking, no schedule table. Padding gathers hit the same 2 lines -> ~free.
// Rationale: effective gather concurrency measured ~12 instrs/CU regardless of
// waves (R1) or per-wave depth (R4) -> if the cap is instruction-slots, 2.2x
// fewer instructions is up to 2x on the edge phase; if it's line-slots, this
// is neutral (clean discriminating test; R2's attempt never ran correctly).
// Flush: cross-quarter shfl_xor(16/32) reduce; normalize by TRUE count from
// cnt[] (offs are padded now); quarter-0 writes the 256B row as uint4.
template <int RELU, int OUTBF>
__global__ __launch_bounds__(512, 4) void k_fused(
    const unsigned short* __restrict__ xb,   // [N+1][128] bf16 (row NN = zeros)
    const unsigned short* __restrict__ wl,   // [9][128][128] n-major bf16
    const int* __restrict__ offs, const int* __restrict__ csr,
    const int* __restrict__ cnt,
    const float* __restrict__ bias, void* __restrict__ outp) {
  __shared__ unsigned int sAgg32[32 * RSTRIDE];    // [32 nodes][9*128+8] bf16, 74240 B
  const unsigned short* sAggH = (const unsigned short*)sAgg32;

  const int tid = threadIdx.x;
  const int w = tid >> 6;                          // 8 waves
  const int lane = tid & 63;
  const int m = lane & 15, q = lane >> 4;
  const int qq = q;                                // edge-quarter in gathers
  const int dlo = (lane & 15) * 8;                 // dim offset (shorts)
  const int n0 = blockIdx.x * 32;
  const int k0 = n0 * NR;

  // this wave's 33 PADDED key offsets, one per lane (lane 0..32)
  int oidx = k0 + 32 * w + lane;
  if (oidx > NKEY) oidx = NKEY;
  const int offv = offs[oidx];
  const int p0 = __builtin_amdgcn_readlane(offv, 0);
  const int p1 = __builtin_amdgcn_readlane(offv, 32);
  // true per-key counts (for mean normalization)
  const int tcv = cnt[k0 + 32 * w + (lane & 31)];

  // root row for this wave's 4 nodes: xb -> sAgg slot 8 (bf16 passthrough)
#pragma unroll
  for (int i = 0; i < 4; i++) {
    int node = 4 * w + i;
    unsigned int v = *(const unsigned int*)(xb + (size_t)(n0 + node) * DD + 2 * lane);
    sAgg32[node * RSTRIDE + 8 * 64 + lane] = v;
  }

  // ---- edge phase ----
  int kloc = 0;
  int kend = __builtin_amdgcn_readlane(offv, 1);
  float acc[8] = {0.f, 0.f, 0.f, 0.f, 0.f, 0.f, 0.f, 0.f};

  // csr window: pv0 covers [wbase, wbase+64) (the only one read); pv1 covers
  // [wbase+64, wbase+128), a pure prefetch swapped in at the 64-edge boundary.
  int wbase = p0;
  int pv0 = csr[wbase + lane];
  int pv1 = csr[wbase + 64 + lane];

#define ISSUE4(DST, POS) do {                                                \
    if ((POS) - wbase == 64) {                                               \
      wbase += 64; pv0 = pv1; pv1 = csr[wbase + 64 + lane];                  \
    }                                                                        \
    int src_ = __shfl(pv0, (POS) - wbase + qq);                              \
    (DST) = *(const short8*)(xb + (size_t)src_ * DD + dlo);                  \
  } while (0)

#define FLUSHK() do {                                                        \
    _Pragma("unroll") for (int e_ = 0; e_ < 8; e_++) {                       \
      acc[e_] += __shfl_xor(acc[e_], 16);                                    \
      acc[e_] += __shfl_xor(acc[e_], 32);                                    \
    }                                                                        \
    float nm_ = __builtin_amdgcn_rcpf(                                       \
        fmaxf((float)__builtin_amdgcn_readlane(tcv, kloc), 1.f));            \
    if (qq == 0) {                                                           \
      uint4 u_;                                                              \
      u_.x = (unsigned)f2bf(acc[0]*nm_) | ((unsigned)f2bf(acc[1]*nm_) << 16);\
      u_.y = (unsigned)f2bf(acc[2]*nm_) | ((unsigned)f2bf(acc[3]*nm_) << 16);\
      u_.z = (unsigned)f2bf(acc[4]*nm_) | ((unsigned)f2bf(acc[5]*nm_) << 16);\
      u_.w = (unsigned)f2bf(acc[6]*nm_) | ((unsigned)f2bf(acc[7]*nm_) << 16);\
      int node_ = 4 * w + (kloc >> 3);                                       \
      *(uint4*)&sAgg32[node_ * RSTRIDE + (kloc & 7) * 64 + 4 * m] = u_;      \
    }                                                                        \
    _Pragma("unroll") for (int e_ = 0; e_ < 8; e_++) acc[e_] = 0.f;          \
    kloc++;                                                                  \
    kend = __builtin_amdgcn_readlane(offv, kloc + 1);                        \
  } while (0)

#define CONSUME4(V, POS) do {                                                \
    if ((POS) < p1) {                                                        \
      while ((POS) >= kend) FLUSHK();                                        \
      _Pragma("unroll") for (int e_ = 0; e_ < 8; e_++)                       \
        acc[e_] += bf2f((unsigned short)(V)[e_]);                            \
    }                                                                        \
  } while (0)

  short8 va[4], vb[4];
#pragma unroll
  for (int j = 0; j < 4; j++) ISSUE4(va[j], p0 + 4 * j);     // prologue

  for (int base = p0; base < p1; base += 32) {
#pragma unroll
    for (int j = 0; j < 4; j++) ISSUE4(vb[j], base + 16 + 4 * j);
#pragma unroll
    for (int j = 0; j < 4; j++) CONSUME4(va[j], base + 4 * j);
#pragma unroll
    for (int j = 0; j < 4; j++) ISSUE4(va[j], base + 32 + 4 * j);
#pragma unroll
    for (int j = 0; j < 4; j++) CONSUME4(vb[j], base + 16 + 4 * j);
  }
  // drain remaining keys (incl. empty -> zero rows via acc=0, nm=1)
  while (kloc < 32) FLUSHK();
#undef ISSUE4
#undef FLUSHK
#undef CONSUME4
  __syncthreads();

  // ---- MFMA phase: wave w -> output cols 16w..16w+15, rows 0..31, 9 mats ----
  f32x4 acc0 = {0.f, 0.f, 0.f, 0.f};              // rows n0+0..15
  f32x4 acc1 = {0.f, 0.f, 0.f, 0.f};              // rows n0+16..31
  for (int mat = 0; mat < 9; mat++) {
    short8 a0[4], a1[4];
#pragma unroll
    for (int ks = 0; ks < 4; ks++) {
      a0[ks] = *(const short8*)(sAggH + m * (2 * RSTRIDE) + mat * 128 + ks * 32 + q * 8);
      a1[ks] = *(const short8*)(sAggH + (m + 16) * (2 * RSTRIDE) + mat * 128 + ks * 32 + q * 8);
    }
    const unsigned short* wr = wl + mat * DD * DD;
#pragma unroll
    for (int ks = 0; ks < 4; ks++) {
      short8 b = *(const short8*)(wr + (w * 16 + m) * DD + ks * 32 + q * 8);
      acc0 = __builtin_amdgcn_mfma_f32_16x16x32_bf16(a0[ks], b, acc0, 0, 0, 0);
      acc1 = __builtin_amdgcn_mfma_f32_16x16x32_bf16(a1[ks], b, acc1, 0, 0, 0);
    }
  }

  // epilogue: C/D row = q*4+i (+16 for acc1), col = w*16+m
  {
    const int c0 = w * 16 + m;
    const float bv = bias[c0];
#pragma unroll
    for (int i = 0; i < 4; i++) {
      int row0 = n0 + q * 4 + i;
      int row1 = row0 + 16;
      float v0 = acc0[i] + bv, v1 = acc1[i] + bv;
      if (RELU) { v0 = fmaxf(v0, 0.f); v1 = fmaxf(v1, 0.f); }
      if (OUTBF) {
        ((unsigned short*)outp)[(size_t)row0 * DD + c0] = f2bf(v0);
        ((unsigned short*)outp)[(size_t)row1 * DD + c0] = f2bf(v1);
      } else {
        ((float*)outp)[(size_t)row0 * DD + c0] = v0;
        ((float*)outp)[(size_t)row1 * DD + c0] = v1;
      }
    }
  }
}

// ---- launch -----------------------------------------------------------------

extern "C" void kernel_launch(void* const* d_in, const int* in_sizes, int n_in,
                              void* d_out, int out_size, void* d_ws, size_t ws_size,
                              hipStream_t stream) {
  const float* x     = (const float*)d_in[0];
  const int*   ei    = (const int*)d_in[1];
  const int*   et    = (const int*)d_in[2];
  const float* W1    = (const float*)d_in[3];
  const float* root1 = (const float*)d_in[4];
  const float* b1    = (const float*)d_in[5];
  const float* W2    = (const float*)d_in[6];
  const float* root2 = (const float*)d_in[7];
  const float* b2    = (const float*)d_in[8];
  float* out = (float*)d_out;

  char* p = (char*)d_ws;
  unsigned short* xb1 = (unsigned short*)p; p += (size_t)(NN + 1) * DD * 2; // 25.6 MB
  unsigned short* xb2 = (unsigned short*)p; p += (size_t)(NN + 1) * DD * 2; // 25.6 MB
  unsigned short* wbf = (unsigned short*)p; p += (size_t)2 * 9 * DD * DD * 2;
  int* cnt  = (int*)p; p += (size_t)NKEY * 4;                           // 3.2 MB
  int* offs = (int*)p; p += (size_t)(NKEY + 16) * 4;                    // 3.2 MB
  int* bsum = (int*)p; p += (size_t)800 * 4;                            // NBLK=782
  int* rank = (int*)p; p += (size_t)NE * 4;                             // 6.4 MB
  int* csr  = (int*)p; p += (size_t)CSRN * 4;                           // 16 MB padded
  // total ~= 81 MB

  const int PREP_B = (NN * DD / 4 + 255) / 256 + 1 + (NKEY + 255) / 256 +
                     (2 * 9 * 16384) / 256 + (CSRN + 255) / 256;
  k_prep<<<PREP_B, 256, 0, stream>>>(x, xb1, xb2, W1, root1, W2, root2, wbf, cnt, csr);
  k_count<<<(NE + 255) / 256, 256, 0, stream>>>(ei, et, cnt, rank);
  k_scan1<<<NBLK, 1024, 0, stream>>>(cnt, offs, bsum);
  k_scan2<<<1, 1024, 0, stream>>>(bsum);
  k_scan3<<<(NKEY + 255) / 256, 256, 0, stream>>>(offs, bsum, cnt);
  k_csr<<<(NE + 255) / 256, 256, 0, stream>>>(ei, et, offs, rank, csr);

  dim3 fgrid(NN / 32);   // 3125
  k_fused<1, 1><<<fgrid, 512, 0, stream>>>(xb1, wbf, offs, csr, cnt, b1, (void*)xb2);
  k_fused<0, 0><<<fgrid, 512, 0, stream>>>(xb2, wbf + 9 * DD * DD, offs, csr, cnt, b2, (void*)out);
}

// Round 8
// 593.682 us; speedup vs baseline: 1.1865x; 1.1865x over previous
//
#include <hip/hip_runtime.h>

#define NN 100000   // nodes
#define NE 1600000  // edges
#define NR 8        // relations
#define DD 128      // feature dim
#define NKEY (NN * NR)               // 800000 (dst,rel) keys
#define NBLK ((NKEY + 1023) / 1024)  // 782 scan blocks
#define RSTRIDE 580                  // sAgg row stride in dwords (R3/R5-proven)

typedef __attribute__((ext_vector_type(8))) short short8;
typedef __attribute__((ext_vector_type(4))) float f32x4;

__device__ __forceinline__ float bf2f(unsigned short u) {
  union { unsigned int i; float f; } c; c.i = ((unsigned int)u) << 16; return c.f;
}
__device__ __forceinline__ unsigned short f2bf(float f) {
  union { float f; unsigned int i; } c; c.f = f;
  unsigned int u = c.i;
  return (unsigned short)((u + 0x7FFFu + ((u >> 16) & 1u)) >> 16);  // RNE
}
__device__ __forceinline__ int qz(float v, float rs) {
  int q = (int)rintf(v * rs);                      // clamp: rounding can hit 128
  return q > 127 ? 127 : (q < -127 ? -127 : q);
}

template <bool Q8> struct GTsel { using T = ushort2; };
template <> struct GTsel<true> { using T = unsigned short; };

// ---- fused preprocessing: edge-count (latency-bound, FIRST so the BW-bound
// cast/wtrans blocks fill its atomic bubbles) + x-cast (bf16 + int8-per-row-
// scale) + weight transpose. cnt is pre-zeroed by hipMemsetAsync.
__global__ __launch_bounds__(256) void k_prep(
    const float* __restrict__ x, unsigned short* __restrict__ xb,
    unsigned char* __restrict__ x8, float* __restrict__ sc,
    const float* __restrict__ W1, const float* __restrict__ root1,
    const float* __restrict__ W2, const float* __restrict__ root2,
    unsigned short* __restrict__ wbf, int* __restrict__ cnt,
    const int* __restrict__ ei, const int* __restrict__ et,
    int* __restrict__ rank) {
  const int COUNT_B = (NE + 255) / 256;            // 6250
  const int CAST_B  = NN * DD / 4 / 256;           // 12500 exact
  int b = blockIdx.x, t = threadIdx.x;
  if (b < COUNT_B) {
    int e = b * 256 + t;
    if (e < NE) {
      int dst = ei[NE + e];
      int r = et[e];
      rank[e] = atomicAdd(&cnt[dst * NR + r], 1);  // cnt holds TRUE counts after
    }
  } else if (b < COUNT_B + CAST_B) {
    int i = (b - COUNT_B) * 256 + t;               // float4 units, exact
    float4 f = ((const float4*)x)[i];
    ushort4 u;
    u.x = f2bf(f.x); u.y = f2bf(f.y); u.z = f2bf(f.z); u.w = f2bf(f.w);
    ((ushort4*)xb)[i] = u;
    // per-row (128-dim) absmax over the 32 lanes holding this row
    float m = fmaxf(fmaxf(fabsf(f.x), fabsf(f.y)), fmaxf(fabsf(f.z), fabsf(f.w)));
#pragma unroll
    for (int k = 1; k < 32; k <<= 1) m = fmaxf(m, __shfl_xor(m, k));
    m = fmaxf(m, 1e-20f);
    float s = m * (1.0f / 127.0f);
    float rs = 127.0f / m;
    int q0 = qz(f.x, rs), q1 = qz(f.y, rs), q2 = qz(f.z, rs), q3 = qz(f.w, rs);
    unsigned int pk = (unsigned)(q0 & 0xff) | ((unsigned)(q1 & 0xff) << 8) |
                      ((unsigned)(q2 & 0xff) << 16) | ((unsigned)(q3 & 0xff) << 24);
    ((unsigned int*)x8)[i] = pk;
    if ((t & 31) == 0) sc[i >> 5] = s;             // row index = i/32
  } else {
    int idx = (b - COUNT_B - CAST_B) * 256 + t;    // 2*9*16384 total, exact
    int layer = idx / (9 * 16384);
    int rem = idx % (9 * 16384);
    int r = rem / 16384;
    int nk = rem % 16384;
    int n = nk >> 7, k = nk & 127;
    float v;
    if (r < 8) v = (layer ? W2 : W1)[r * 16384 + k * 128 + n];
    else       v = (layer ? root2 : root1)[k * 128 + n];
    wbf[idx] = f2bf(v);
  }
}

// hierarchical exclusive scan over NKEY elements — shfl-based
__global__ __launch_bounds__(1024) void k_scan1(
    const int* __restrict__ cnt, int* __restrict__ offs, int* __restrict__ bsum) {
  __shared__ int sw[16];
  int t = threadIdx.x, b = blockIdx.x;
  int lane = t & 63, wid = t >> 6;
  int i = b * 1024 + t;
  int v = (i < NKEY) ? cnt[i] : 0;
  int x = v;
#pragma unroll
  for (int o = 1; o < 64; o <<= 1) {
    int y = __shfl_up(x, o);
    if (lane >= o) x += y;
  }
  if (lane == 63) sw[wid] = x;
  __syncthreads();
  if (wid == 0) {
    int s = (lane < 16) ? sw[lane] : 0;
#pragma unroll
    for (int o = 1; o < 16; o <<= 1) {
      int y = __shfl_up(s, o);
      if (lane >= o) s += y;
    }
    if (lane < 16) sw[lane] = s;
  }
  __syncthreads();
  int base = (wid > 0) ? sw[wid - 1] : 0;
  if (i < NKEY) offs[i] = base + x - v;
  if (t == 1023) bsum[b] = base + x;
}

__global__ __launch_bounds__(1024) void k_scan2(int* __restrict__ bsum) {
  __shared__ int sw[16];
  int t = threadIdx.x;
  int lane = t & 63, wid = t >> 6;
  int v = (t < NBLK) ? bsum[t] : 0;
  int x = v;
#pragma unroll
  for (int o = 1; o < 64; o <<= 1) {
    int y = __shfl_up(x, o);
    if (lane >= o) x += y;
  }
  if (lane == 63) sw[wid] = x;
  __syncthreads();
  if (wid == 0) {
    int s = (lane < 16) ? sw[lane] : 0;
#pragma unroll
    for (int o = 1; o < 16; o <<= 1) {
      int y = __shfl_up(s, o);
      if (lane >= o) s += y;
    }
    if (lane < 16) sw[lane] = s;
  }
  __syncthreads();
  int base = (wid > 0) ? sw[wid - 1] : 0;
  if (t < NBLK) bsum[t] = base + x - v;
}

__global__ __launch_bounds__(256) void k_scan3(
    int* __restrict__ offs, const int* __restrict__ bsum,
    int* __restrict__ csr, float* __restrict__ csrs) {
  int i = blockIdx.x * 256 + threadIdx.x;
  if (i < NKEY) offs[i] += bsum[i >> 10];
  if (i == 0) offs[NKEY] = NE;
  if (i < 192) { csr[NE + i] = 0; csrs[NE + i] = 0.f; }  // pad for window prefetch
}

// pure scatter, no atomics; piggybacks the per-row int8 scale into csrs so the
// edge phase reads scales SEQUENTIALLY (no extra random gather per edge)
__global__ __launch_bounds__(256) void k_csr(
    const int* __restrict__ ei, const int* __restrict__ et,
    const int* __restrict__ offs, const int* __restrict__ rank,
    const float* __restrict__ sc,
    int* __restrict__ csr, float* __restrict__ csrs) {
  int e = blockIdx.x * 256 + threadIdx.x;
  if (e < NE) {
    int src = ei[e];
    int key = ei[NE + e] * NR + et[e];
    int slot = offs[key] + rank[e];
    csr[slot] = src;
    csrs[slot] = sc[src];
  }
}

// ---- fused per-layer kernel (R5 structure: DEPTH8 ping-pong, 32 nodes/block)
// GQ8=1: gathers 128B int8 rows (ONE cache line per edge — the line count is
// the edge-phase wall per R1/R3/R4/R6) decoded as q*s with the per-row scale s
// delivered via the sequential csrs window (readlane -> SGPR -> v_fmac).
// GQ8=0: R5-exact 256B bf16 row gather (layer 2).
template <int RELU, int OUTBF, int GQ8>
__global__ __launch_bounds__(512, 4) void k_fused(
    const unsigned char* __restrict__ gx,    // gather rows (int8[128] or bf16[128])
    const float* __restrict__ gs,            // per-edge scales (csrs), GQ8 only
    const unsigned short* __restrict__ xbr,  // [N][128] bf16 root source
    const unsigned short* __restrict__ wl,   // [9][128][128] n-major bf16
    const int* __restrict__ offs, const int* __restrict__ csr,
    const float* __restrict__ bias, void* __restrict__ outp) {
  __shared__ unsigned int sAgg32[32 * RSTRIDE];    // [32 nodes][9*128+8] bf16, 74240 B
  const unsigned short* sAggH = (const unsigned short*)sAgg32;

  const int tid = threadIdx.x;
  const int w = tid >> 6;                          // 8 waves
  const int lane = tid & 63;
  const int m = lane & 15, q = lane >> 4;
  const int n0 = blockIdx.x * 32;
  const int k0 = n0 * NR;

  // this wave's 33 key offsets, one per lane (lane 0..32)
  int oidx = k0 + 32 * w + lane;
  if (oidx > NKEY) oidx = NKEY;
  const int offv = offs[oidx];
  const int p0 = __builtin_amdgcn_readlane(offv, 0);
  const int p1 = __builtin_amdgcn_readlane(offv, 32);

  // root row for this wave's 4 nodes: xbr -> sAgg slot 8 (bf16 passthrough)
#pragma unroll
  for (int i = 0; i < 4; i++) {
    int node = 4 * w + i;
    unsigned int v = *(const unsigned int*)(xbr + (size_t)(n0 + node) * DD + 2 * lane);
    sAgg32[node * RSTRIDE + 8 * 64 + lane] = v;
  }

  // ---- edge phase ----
  int kloc = 0;
  int kbeg = p0;
  int kend = __builtin_amdgcn_readlane(offv, 1);
  float ax = 0.f, ay = 0.f;

  // csr window: pv0/sv0 cover [wbase, wbase+64) (the only ones read); pv1/sv1
  // cover [wbase+64, wbase+128), pure prefetch swapped at the 64-edge boundary.
  int wbase = p0;
  int pv0 = csr[wbase + lane];
  int pv1 = csr[wbase + 64 + lane];
  float sv0 = 0.f, sv1 = 0.f;
  if constexpr (GQ8) {
    sv0 = gs[wbase + lane];
    sv1 = gs[wbase + 64 + lane];
  }

#define ISSUE8(DST, SD, NB) do {                                             \
    if ((NB) - wbase == 64) {                                                \
      wbase += 64; pv0 = pv1; pv1 = csr[wbase + 64 + lane];                  \
      if constexpr (GQ8) { sv0 = sv1; sv1 = gs[wbase + 64 + lane]; }         \
    }                                                                        \
    const int ib_ = (NB) - wbase;                                            \
    _Pragma("unroll") for (int j_ = 0; j_ < 8; j_++) {                       \
      unsigned s_ = (unsigned)__builtin_amdgcn_readlane(pv0, ib_ + j_);      \
      if constexpr (GQ8) {                                                   \
        (DST)[j_] = *(const unsigned short*)(gx + (size_t)s_ * 128 + 2 * lane); \
        (SD)[j_] = __uint_as_float(__builtin_amdgcn_readlane(                \
            __float_as_uint(sv0), ib_ + j_));                                \
      } else {                                                               \
        (DST)[j_] = *(const ushort2*)(gx + (size_t)s_ * 256 + 4 * lane);     \
      }                                                                      \
    }                                                                        \
  } while (0)

#define CONSUME8(V, S, B0) do {                                              \
    _Pragma("unroll") for (int j_ = 0; j_ < 8; j_++) {                       \
      if ((B0) + j_ < p1) {                                                  \
        while ((B0) + j_ >= kend) {                                          \
          float nm_ = __builtin_amdgcn_rcpf(fmaxf((float)(kend - kbeg), 1.f)); \
          unsigned lo_ = f2bf(ax * nm_), hi_ = f2bf(ay * nm_);               \
          int node_ = 4 * w + (kloc >> 3);                                   \
          sAgg32[node_ * RSTRIDE + (kloc & 7) * 64 + lane] = lo_ | (hi_ << 16); \
          ax = 0.f; ay = 0.f;                                                \
          kloc++;                                                            \
          kbeg = kend;                                                       \
          kend = __builtin_amdgcn_readlane(offv, kloc + 1);                  \
        }                                                                    \
        if constexpr (GQ8) {                                                 \
          unsigned u_ = (V)[j_];                                             \
          ax += (S)[j_] * (float)(signed char)(u_ & 0xff);                   \
          ay += (S)[j_] * (float)(signed char)(u_ >> 8);                     \
        } else {                                                             \
          ax += bf2f((V)[j_].x);                                             \
          ay += bf2f((V)[j_].y);                                             \
        }                                                                    \
      }                                                                      \
    }                                                                        \
  } while (0)

  typename GTsel<GQ8 != 0>::T va[8], vb[8];
  float sa[8], sb[8];
  ISSUE8(va, sa, p0);                              // prologue: edges p0..p0+7

  for (int base = p0; base < p1; base += 16) {
    ISSUE8(vb, sb, base + 8);                      // issue edges base+8..+15
    CONSUME8(va, sa, base);                        // consume edges base..+7
    ISSUE8(va, sa, base + 16);                     // issue edges base+16..+23
    CONSUME8(vb, sb, base + 8);                    // consume edges base+8..+15
  }
  // drain remaining keys (incl. empty)
  while (kloc < 32) {
    float nm = __builtin_amdgcn_rcpf(fmaxf((float)(kend - kbeg), 1.f));
    unsigned lo = f2bf(ax * nm), hi = f2bf(ay * nm);
    int node = 4 * w + (kloc >> 3);
    sAgg32[node * RSTRIDE + (kloc & 7) * 64 + lane] = lo | (hi << 16);
    ax = 0.f; ay = 0.f;
    kloc++;
    kbeg = kend;
    kend = (kloc < 32) ? __builtin_amdgcn_readlane(offv, kloc + 1) : kend;
  }
#undef ISSUE8
#undef CONSUME8
  __syncthreads();

  // ---- MFMA phase: wave w -> output cols 16w..16w+15, rows 0..31, 9 mats ----
  f32x4 acc0 = {0.f, 0.f, 0.f, 0.f};              // rows n0+0..15
  f32x4 acc1 = {0.f, 0.f, 0.f, 0.f};              // rows n0+16..31
  for (int mat = 0; mat < 9; mat++) {
    short8 a0[4], a1[4];
#pragma unroll
    for (int ks = 0; ks < 4; ks++) {
      a0[ks] = *(const short8*)(sAggH + m * (2 * RSTRIDE) + mat * 128 + ks * 32 + q * 8);
      a1[ks] = *(const short8*)(sAggH + (m + 16) * (2 * RSTRIDE) + mat * 128 + ks * 32 + q * 8);
    }
    const unsigned short* wr = wl + mat * DD * DD;
#pragma unroll
    for (int ks = 0; ks < 4; ks++) {
      short8 b = *(const short8*)(wr + (w * 16 + m) * DD + ks * 32 + q * 8);
      acc0 = __builtin_amdgcn_mfma_f32_16x16x32_bf16(a0[ks], b, acc0, 0, 0, 0);
      acc1 = __builtin_amdgcn_mfma_f32_16x16x32_bf16(a1[ks], b, acc1, 0, 0, 0);
    }
  }

  // epilogue: C/D row = q*4+i (+16 for acc1), col = w*16+m
  {
    const int c0 = w * 16 + m;
    const float bv = bias[c0];
#pragma unroll
    for (int i = 0; i < 4; i++) {
      int row0 = n0 + q * 4 + i;
      int row1 = row0 + 16;
      float v0 = acc0[i] + bv, v1 = acc1[i] + bv;
      if (RELU) { v0 = fmaxf(v0, 0.f); v1 = fmaxf(v1, 0.f); }
      if (OUTBF) {
        ((unsigned short*)outp)[(size_t)row0 * DD + c0] = f2bf(v0);
        ((unsigned short*)outp)[(size_t)row1 * DD + c0] = f2bf(v1);
      } else {
        ((float*)outp)[(size_t)row0 * DD + c0] = v0;
        ((float*)outp)[(size_t)row1 * DD + c0] = v1;
      }
    }
  }
}

// ---- launch -----------------------------------------------------------------

extern "C" void kernel_launch(void* const* d_in, const int* in_sizes, int n_in,
                              void* d_out, int out_size, void* d_ws, size_t ws_size,
                              hipStream_t stream) {
  const float* x     = (const float*)d_in[0];
  const int*   ei    = (const int*)d_in[1];
  const int*   et    = (const int*)d_in[2];
  const float* W1    = (const float*)d_in[3];
  const float* root1 = (const float*)d_in[4];
  const float* b1    = (const float*)d_in[5];
  const float* W2    = (const float*)d_in[6];
  const float* root2 = (const float*)d_in[7];
  const float* b2    = (const float*)d_in[8];
  float* out = (float*)d_out;

  char* p = (char*)d_ws;
  unsigned short* xb1 = (unsigned short*)p; p += (size_t)NN * DD * 2;   // 25.6 MB
  unsigned short* xb2 = (unsigned short*)p; p += (size_t)NN * DD * 2;   // 25.6 MB
  unsigned char*  x8  = (unsigned char*)p;  p += (size_t)NN * DD;       // 12.8 MB
  float* sc = (float*)p; p += (size_t)NN * 4;                           // 0.4 MB
  unsigned short* wbf = (unsigned short*)p; p += (size_t)2 * 9 * DD * DD * 2;
  int* cnt  = (int*)p; p += (size_t)NKEY * 4;                           // 3.2 MB
  int* offs = (int*)p; p += (size_t)(NKEY + 16) * 4;                    // 3.2 MB
  int* bsum = (int*)p; p += (size_t)800 * 4;                            // NBLK=782
  int* rank = (int*)p; p += (size_t)NE * 4;                             // 6.4 MB
  int* csr  = (int*)p; p += (size_t)(NE + 192) * 4;                     // 6.4 MB (+pad)
  float* csrs = (float*)p; p += (size_t)(NE + 192) * 4;                 // 6.4 MB (+pad)
  // total ~= 90 MB

  hipMemsetAsync(cnt, 0, (size_t)NKEY * 4, stream);

  const int PREP_B = (NE + 255) / 256 + NN * DD / 4 / 256 + (2 * 9 * 16384) / 256;
  k_prep<<<PREP_B, 256, 0, stream>>>(x, xb1, x8, sc, W1, root1, W2, root2, wbf,
                                     cnt, ei, et, rank);
  k_scan1<<<NBLK, 1024, 0, stream>>>(cnt, offs, bsum);
  k_scan2<<<1, 1024, 0, stream>>>(bsum);
  k_scan3<<<(NKEY + 255) / 256, 256, 0, stream>>>(offs, bsum, csr, csrs);
  k_csr<<<(NE + 255) / 256, 256, 0, stream>>>(ei, et, offs, rank, sc, csr, csrs);

  dim3 fgrid(NN / 32);   // 3125
  k_fused<1, 1, 1><<<fgrid, 512, 0, stream>>>(x8, csrs, xb1, wbf, offs, csr,
                                              b1, (void*)xb2);
  k_fused<0, 0, 0><<<fgrid, 512, 0, stream>>>((const unsigned char*)xb2, csrs, xb2,
                                              wbf + 9 * DD * DD, offs, csr,
                                              b2, (void*)out);
}